// Round 1
// baseline (4496.022 us; speedup 1.0000x reference)
//
#include <hip/hip_runtime.h>

#define NH 16
#define HD 64

// ---------------------------------------------------------------------------
// C[M,N] = A[M,K] @ B[K,N] + bias[N]   (fp32, row-major)
// BM=BN=64, BK=32, 256 threads, 4x4 acc per thread.
// ---------------------------------------------------------------------------
template<int BM, int BN, int BK>
__global__ __launch_bounds__(256)
void gemm_bias(const float* __restrict__ A, const float* __restrict__ B,
               const float* __restrict__ bias, float* __restrict__ C,
               int M, int N, int K) {
    __shared__ float As[BK][BM + 1];   // transposed: As[k][m]
    __shared__ float Bs[BK][BN + 4];   // +4 pad keeps float4 alignment

    const int tid = threadIdx.x;
    const int tx = tid & 15;           // 16 col groups
    const int ty = tid >> 4;           // 16 row groups
    const int row0 = blockIdx.y * BM;
    const int col0 = blockIdx.x * BN;

    float acc[4][4] = {};

    for (int k0 = 0; k0 < K; k0 += BK) {
        // A tile: BM x BK = 2048 floats -> 512 float4 -> 2 per thread
        #pragma unroll
        for (int i = 0; i < (BM * BK) / (256 * 4); ++i) {
            int idx = tid + i * 256;
            int r   = idx / (BK / 4);
            int c4  = (idx % (BK / 4)) * 4;
            float4 v = *reinterpret_cast<const float4*>(
                &A[(size_t)(row0 + r) * K + k0 + c4]);
            As[c4 + 0][r] = v.x; As[c4 + 1][r] = v.y;
            As[c4 + 2][r] = v.z; As[c4 + 3][r] = v.w;
        }
        // B tile: BK x BN = 2048 floats
        #pragma unroll
        for (int i = 0; i < (BK * BN) / (256 * 4); ++i) {
            int idx = tid + i * 256;
            int r   = idx / (BN / 4);
            int c4  = (idx % (BN / 4)) * 4;
            float4 v = *reinterpret_cast<const float4*>(
                &B[(size_t)(k0 + r) * N + col0 + c4]);
            *reinterpret_cast<float4*>(&Bs[r][c4]) = v;
        }
        __syncthreads();

        #pragma unroll
        for (int kk = 0; kk < BK; ++kk) {
            float a[4], bb[4];
            #pragma unroll
            for (int i = 0; i < 4; ++i) a[i] = As[kk][ty * 4 + i];
            float4 bv = *reinterpret_cast<const float4*>(&Bs[kk][tx * 4]);
            bb[0] = bv.x; bb[1] = bv.y; bb[2] = bv.z; bb[3] = bv.w;
            #pragma unroll
            for (int i = 0; i < 4; ++i)
                #pragma unroll
                for (int j = 0; j < 4; ++j)
                    acc[i][j] = fmaf(a[i], bb[j], acc[i][j]);
        }
        __syncthreads();
    }

    #pragma unroll
    for (int i = 0; i < 4; ++i) {
        int r = row0 + ty * 4 + i;
        #pragma unroll
        for (int j = 0; j < 4; ++j) {
            int c = col0 + tx * 4 + j;
            C[(size_t)r * N + c] = acc[i][j] + bias[c];
        }
    }
}

// ---------------------------------------------------------------------------
// Fused causal attention, flash-style online softmax.
// One block (256 threads) per (b, h, 64-row q block). 64-key tiles.
// qkv layout: [B, S, 3*D]; q at +0, k at +D, v at +2D, head h at h*HD.
// out layout: [B, S, D] (heads merged).
// ---------------------------------------------------------------------------
__global__ __launch_bounds__(256)
void attn_fused(const float* __restrict__ qkv, float* __restrict__ out,
                int B, int S, int D3, int Dm) {
    const int h  = blockIdx.y & (NH - 1);
    const int b  = blockIdx.y / NH;
    const int q0 = blockIdx.x * 64;

    __shared__ float Qs[64][HD + 1];
    __shared__ float KsT[HD][64 + 1];   // KsT[d][k]
    __shared__ float Vs[64][HD + 1];
    __shared__ float Ps[64][64 + 1];

    const int tid = threadIdx.x;
    const size_t baseQ = (size_t)b * S * D3 + (size_t)h * HD;
    const size_t baseK = baseQ + (size_t)Dm;
    const size_t baseV = baseQ + 2 * (size_t)Dm;

    // Load Q tile (64 x 64)
    #pragma unroll
    for (int i = 0; i < 4; ++i) {
        int idx = tid + i * 256;
        int r = idx >> 4;
        int c = (idx & 15) << 2;
        float4 v = *reinterpret_cast<const float4*>(
            &qkv[baseQ + (size_t)(q0 + r) * D3 + c]);
        Qs[r][c] = v.x; Qs[r][c + 1] = v.y; Qs[r][c + 2] = v.z; Qs[r][c + 3] = v.w;
    }

    const int r  = tid >> 2;          // q row within tile
    const int cq = (tid & 3) << 4;    // col offset {0,16,32,48}
    const float scale = 0.125f;       // 1/sqrt(64)

    float m = -1e30f, l = 0.f;
    float o[16];
    #pragma unroll
    for (int j = 0; j < 16; ++j) o[j] = 0.f;

    const int nkt = blockIdx.x + 1;   // causal: tiles 0..q0/64
    for (int kt = 0; kt < nkt; ++kt) {
        const int k0 = kt * 64;
        __syncthreads();   // previous iteration done with Ks/Vs/Ps

        #pragma unroll
        for (int i = 0; i < 4; ++i) {
            int idx = tid + i * 256;
            int rr = idx >> 4;
            int c  = (idx & 15) << 2;
            float4 kv = *reinterpret_cast<const float4*>(
                &qkv[baseK + (size_t)(k0 + rr) * D3 + c]);
            KsT[c][rr] = kv.x; KsT[c + 1][rr] = kv.y;
            KsT[c + 2][rr] = kv.z; KsT[c + 3][rr] = kv.w;
            float4 vv = *reinterpret_cast<const float4*>(
                &qkv[baseV + (size_t)(k0 + rr) * D3 + c]);
            Vs[rr][c] = vv.x; Vs[rr][c + 1] = vv.y;
            Vs[rr][c + 2] = vv.z; Vs[rr][c + 3] = vv.w;
        }
        __syncthreads();

        // S = Q K^T for this thread's 16 columns
        float s[16];
        #pragma unroll
        for (int j = 0; j < 16; ++j) s[j] = 0.f;
        for (int d = 0; d < HD; ++d) {
            float qv = Qs[r][d];
            #pragma unroll
            for (int j = 0; j < 16; ++j)
                s[j] = fmaf(qv, KsT[d][cq + j], s[j]);
        }

        // causal mask + scale (mask uses -10000 bias, matching reference)
        const int qg = q0 + r;
        #pragma unroll
        for (int j = 0; j < 16; ++j) {
            int kg = k0 + cq + j;
            s[j] = (kg <= qg) ? s[j] * scale : -10000.0f;
        }

        // online softmax: row max over 64 cols (4 lanes/row)
        float tmax = s[0];
        #pragma unroll
        for (int j = 1; j < 16; ++j) tmax = fmaxf(tmax, s[j]);
        tmax = fmaxf(tmax, __shfl_xor(tmax, 1));
        tmax = fmaxf(tmax, __shfl_xor(tmax, 2));
        const float mnew = fmaxf(m, tmax);
        const float alpha = __expf(m - mnew);
        float tsum = 0.f;
        #pragma unroll
        for (int j = 0; j < 16; ++j) { s[j] = __expf(s[j] - mnew); tsum += s[j]; }
        tsum += __shfl_xor(tsum, 1);
        tsum += __shfl_xor(tsum, 2);
        l = l * alpha + tsum;
        m = mnew;

        #pragma unroll
        for (int j = 0; j < 16; ++j) { o[j] *= alpha; Ps[r][cq + j] = s[j]; }
        __syncthreads();

        // O += P @ V  (this thread: row r, dims cq..cq+15)
        for (int k = 0; k < 64; ++k) {
            float p = Ps[r][k];
            #pragma unroll
            for (int j = 0; j < 16; ++j)
                o[j] = fmaf(p, Vs[k][cq + j], o[j]);
        }
    }

    const float inv = 1.0f / l;
    const size_t baseO = ((size_t)b * S + q0 + r) * Dm + (size_t)h * HD + cq;
    #pragma unroll
    for (int j = 0; j < 16; ++j) out[baseO + j] = o[j] * inv;
}

// ---------------------------------------------------------------------------
extern "C" void kernel_launch(void* const* d_in, const int* in_sizes, int n_in,
                              void* d_out, int out_size, void* d_ws, size_t ws_size,
                              hipStream_t stream) {
    const float* x    = (const float*)d_in[0];  // [B,S,D]
    const float* Wqkv = (const float*)d_in[1];  // [D,3D]
    const float* bqkv = (const float*)d_in[2];  // [3D]
    const float* Wp   = (const float*)d_in[3];  // [D,D]
    const float* bp   = (const float*)d_in[4];  // [D]
    float* out = (float*)d_out;

    const int B = 4, S = 2048, D = 1024;
    const int M = B * S;                 // 8192

    // workspace: qkv [M,3D] (96 MB) + attn_out [M,D] (32 MB) = 128 MB
    float* qkv   = (float*)d_ws;
    float* attno = qkv + (size_t)M * 3 * D;

    dim3 blk(256);
    gemm_bias<64, 64, 32><<<dim3(3 * D / 64, M / 64), blk, 0, stream>>>(
        x, Wqkv, bqkv, qkv, M, 3 * D, D);
    attn_fused<<<dim3(S / 64, B * NH), blk, 0, stream>>>(
        qkv, attno, B, S, 3 * D, D);
    gemm_bias<64, 64, 32><<<dim3(D / 64, M / 64), blk, 0, stream>>>(
        attno, Wp, bp, out, M, D, D);
}

// Round 2
// 1224.124 us; speedup vs baseline: 3.6728x; 3.6728x over previous
//
#include <hip/hip_runtime.h>

#define NH 16
#define HD 64

typedef __attribute__((ext_vector_type(8))) short bf16x8;
typedef __attribute__((ext_vector_type(4))) float f32x4;
typedef __attribute__((ext_vector_type(8))) unsigned short us8;
typedef __attribute__((ext_vector_type(4))) unsigned short us4;

__device__ __forceinline__ unsigned short f2b(float f) {
    union { float f; unsigned u; } v; v.f = f;
    unsigned r = v.u + 0x7FFFu + ((v.u >> 16) & 1u);   // RNE
    return (unsigned short)(r >> 16);
}

// ---------------------------------------------------------------------------
// Stage a 64x64 bf16 tile (rows = 128B) from global into LDS with XOR swizzle:
// lds byte = row*128 + (col_byte ^ ((row&7)<<4)).  256 threads, 2 passes.
// ---------------------------------------------------------------------------
__device__ __forceinline__ void stage64(unsigned short* dst,
                                        const unsigned short* src, int stride) {
    const int tid = threadIdx.x;
    const int r0 = tid >> 3;
    const int sb = (tid & 7) << 4;   // byte slot within row
    #pragma unroll
    for (int p = 0; p < 2; ++p) {
        int r = r0 + p * 32;
        us8 v = *reinterpret_cast<const us8*>(src + (size_t)r * stride + (sb >> 1));
        int cb = sb ^ ((r & 7) << 4);
        *reinterpret_cast<us8*>(reinterpret_cast<char*>(dst) + r * 128 + cb) = v;
    }
}

// Fragment load: lane l -> row row0+(l&15), bytes [ks*64 + (l>>4)*16, +16)
__device__ __forceinline__ bf16x8 frag_ld(const unsigned short* base, int row0, int ks) {
    const int lane = threadIdx.x & 63;
    const int r = row0 + (lane & 15);
    int cb = (ks << 6) + (lane & 48);
    cb ^= ((r & 7) << 4);
    return *reinterpret_cast<const bf16x8*>(
        reinterpret_cast<const char*>(base) + r * 128 + cb);
}

// ---------------------------------------------------------------------------
// QKV GEMM: qkv = x @ Wqkv + b, emitting bf16 Q,K [B,H,S,64] and V^T [B,H,64,S]
// ---------------------------------------------------------------------------
__global__ __launch_bounds__(256)
void gemm_qkv(const float* __restrict__ A, const float* __restrict__ B,
              const float* __restrict__ bias,
              unsigned short* __restrict__ qb, unsigned short* __restrict__ kb,
              unsigned short* __restrict__ vtb, int M, int N, int K) {
    const int BM = 64, BN = 64, BK = 32;
    __shared__ float As[32][64 + 1];
    __shared__ float Bs[32][64 + 4];

    const int tid = threadIdx.x;
    const int tx = tid & 15;
    const int ty = tid >> 4;
    const int row0 = blockIdx.y * BM;
    const int col0 = blockIdx.x * BN;

    float acc[4][4] = {};

    for (int k0 = 0; k0 < K; k0 += BK) {
        #pragma unroll
        for (int i = 0; i < 2; ++i) {
            int idx = tid + i * 256;
            int r = idx / (BK / 4);
            int c4 = (idx % (BK / 4)) * 4;
            float4 v = *reinterpret_cast<const float4*>(
                &A[(size_t)(row0 + r) * K + k0 + c4]);
            As[c4 + 0][r] = v.x; As[c4 + 1][r] = v.y;
            As[c4 + 2][r] = v.z; As[c4 + 3][r] = v.w;
        }
        #pragma unroll
        for (int i = 0; i < 2; ++i) {
            int idx = tid + i * 256;
            int r = idx / (BN / 4);
            int c4 = (idx % (BN / 4)) * 4;
            float4 v = *reinterpret_cast<const float4*>(
                &B[(size_t)(k0 + r) * N + col0 + c4]);
            *reinterpret_cast<float4*>(&Bs[r][c4]) = v;
        }
        __syncthreads();
        #pragma unroll
        for (int kk = 0; kk < BK; ++kk) {
            float a[4];
            #pragma unroll
            for (int i = 0; i < 4; ++i) a[i] = As[kk][ty * 4 + i];
            float4 bv = *reinterpret_cast<const float4*>(&Bs[kk][tx * 4]);
            float bb[4] = {bv.x, bv.y, bv.z, bv.w};
            #pragma unroll
            for (int i = 0; i < 4; ++i)
                #pragma unroll
                for (int j = 0; j < 4; ++j)
                    acc[i][j] = fmaf(a[i], bb[j], acc[i][j]);
        }
        __syncthreads();
    }

    // epilogue: bias + cast + layout-split
    const int r0 = row0 + ty * 4;
    const int c0 = col0 + tx * 4;
    float b4[4];
    #pragma unroll
    for (int j = 0; j < 4; ++j) b4[j] = bias[c0 + j];
    const int seg = c0 >> 10;        // 0=q 1=k 2=v
    const int cc = c0 & 1023;
    const int h = cc >> 6, d = cc & 63;
    const int bb_ = r0 >> 11, s0 = r0 & 2047;

    if (seg < 2) {
        unsigned short* dst = (seg ? kb : qb) + (size_t)(bb_ * NH + h) * 2048 * 64;
        #pragma unroll
        for (int i = 0; i < 4; ++i) {
            us4 w;
            #pragma unroll
            for (int j = 0; j < 4; ++j) w[j] = f2b(acc[i][j] + b4[j]);
            *reinterpret_cast<us4*>(dst + (size_t)(s0 + i) * 64 + d) = w;
        }
    } else {
        unsigned short* dst = vtb + (size_t)(bb_ * NH + h) * 64 * 2048;
        #pragma unroll
        for (int j = 0; j < 4; ++j) {
            us4 w;
            #pragma unroll
            for (int i = 0; i < 4; ++i) w[i] = f2b(acc[i][j] + b4[j]);
            *reinterpret_cast<us4*>(dst + (size_t)(d + j) * 2048 + s0) = w;
        }
    }
}

// ---------------------------------------------------------------------------
// fp32 GEMM + bias (projection)
// ---------------------------------------------------------------------------
__global__ __launch_bounds__(256)
void gemm_bias(const float* __restrict__ A, const float* __restrict__ B,
               const float* __restrict__ bias, float* __restrict__ C,
               int M, int N, int K) {
    const int BM = 64, BN = 64, BK = 32;
    __shared__ float As[32][64 + 1];
    __shared__ float Bs[32][64 + 4];

    const int tid = threadIdx.x;
    const int tx = tid & 15;
    const int ty = tid >> 4;
    const int row0 = blockIdx.y * BM;
    const int col0 = blockIdx.x * BN;

    float acc[4][4] = {};

    for (int k0 = 0; k0 < K; k0 += BK) {
        #pragma unroll
        for (int i = 0; i < 2; ++i) {
            int idx = tid + i * 256;
            int r = idx / (BK / 4);
            int c4 = (idx % (BK / 4)) * 4;
            float4 v = *reinterpret_cast<const float4*>(
                &A[(size_t)(row0 + r) * K + k0 + c4]);
            As[c4 + 0][r] = v.x; As[c4 + 1][r] = v.y;
            As[c4 + 2][r] = v.z; As[c4 + 3][r] = v.w;
        }
        #pragma unroll
        for (int i = 0; i < 2; ++i) {
            int idx = tid + i * 256;
            int r = idx / (BN / 4);
            int c4 = (idx % (BN / 4)) * 4;
            float4 v = *reinterpret_cast<const float4*>(
                &B[(size_t)(k0 + r) * N + col0 + c4]);
            *reinterpret_cast<float4*>(&Bs[r][c4]) = v;
        }
        __syncthreads();
        #pragma unroll
        for (int kk = 0; kk < BK; ++kk) {
            float a[4];
            #pragma unroll
            for (int i = 0; i < 4; ++i) a[i] = As[kk][ty * 4 + i];
            float4 bv = *reinterpret_cast<const float4*>(&Bs[kk][tx * 4]);
            float bb[4] = {bv.x, bv.y, bv.z, bv.w};
            #pragma unroll
            for (int i = 0; i < 4; ++i)
                #pragma unroll
                for (int j = 0; j < 4; ++j)
                    acc[i][j] = fmaf(a[i], bb[j], acc[i][j]);
        }
        __syncthreads();
    }

    #pragma unroll
    for (int i = 0; i < 4; ++i) {
        int r = row0 + ty * 4 + i;
        #pragma unroll
        for (int j = 0; j < 4; ++j) {
            int c = col0 + tx * 4 + j;
            C[(size_t)r * N + c] = acc[i][j] + bias[c];
        }
    }
}

// ---------------------------------------------------------------------------
// MFMA flash attention. Block = 256 thr = 4 waves, 64 q-rows (16/wave),
// KV tiles of 64. Q,K bf16 [B,H,S,64]; V^T bf16 [B,H,64,S]; out fp32 [B,S,D].
// ---------------------------------------------------------------------------
__global__ __launch_bounds__(256)
void attn_mfma(const unsigned short* __restrict__ qb,
               const unsigned short* __restrict__ kb,
               const unsigned short* __restrict__ vtb,
               float* __restrict__ out) {
    const int bh = blockIdx.y;
    const int qt = blockIdx.x;
    const int tid = threadIdx.x;
    const int wid = tid >> 6;
    const int lane = tid & 63;
    const int g = lane >> 4;

    __shared__ __align__(16) unsigned short Qs[64 * 64];
    __shared__ __align__(16) unsigned short Ks[64 * 64];
    __shared__ __align__(16) unsigned short Vs[64 * 64];
    __shared__ __align__(16) unsigned short Ps[4][16 * 64];

    const unsigned short* qg  = qb  + ((size_t)bh * 2048 + (size_t)qt * 64) * 64;
    const unsigned short* kg0 = kb  + (size_t)bh * 2048 * 64;
    const unsigned short* vg0 = vtb + (size_t)bh * 64 * 2048;

    stage64(Qs, qg, 64);
    __syncthreads();
    const bf16x8 qf0 = frag_ld(Qs, wid * 16, 0);
    const bf16x8 qf1 = frag_ld(Qs, wid * 16, 1);

    f32x4 o[4];
    float m_[4], l_[4];
    #pragma unroll
    for (int n = 0; n < 4; ++n) { o[n][0] = 0.f; o[n][1] = 0.f; o[n][2] = 0.f; o[n][3] = 0.f; }
    #pragma unroll
    for (int r = 0; r < 4; ++r) { m_[r] = -1e30f; l_[r] = 0.f; }

    for (int kt = 0; kt <= qt; ++kt) {
        __syncthreads();
        stage64(Ks, kg0 + (size_t)kt * 64 * 64, 64);
        stage64(Vs, vg0 + (size_t)kt * 64, 2048);
        __syncthreads();

        // S = Q K^T
        f32x4 s[4];
        #pragma unroll
        for (int n = 0; n < 4; ++n) { s[n][0] = 0.f; s[n][1] = 0.f; s[n][2] = 0.f; s[n][3] = 0.f; }
        #pragma unroll
        for (int ks = 0; ks < 2; ++ks) {
            bf16x8 a = ks ? qf1 : qf0;
            #pragma unroll
            for (int n = 0; n < 4; ++n)
                s[n] = __builtin_amdgcn_mfma_f32_16x16x32_bf16(
                    a, frag_ld(Ks, n * 16, ks), s[n], 0, 0, 0);
        }

        unsigned short* Pw = Ps[wid];
        const int kc0 = kt * 64 + (lane & 15);
        const int qr0 = qt * 64 + wid * 16 + (g << 2);
        const bool diag = (kt == qt);

        #pragma unroll
        for (int reg = 0; reg < 4; ++reg) {
            float x[4];
            #pragma unroll
            for (int n = 0; n < 4; ++n) {
                x[n] = s[n][reg] * 0.125f;
                if (diag && (kc0 + 16 * n > qr0 + reg)) x[n] = -10000.0f;
            }
            float rmax = fmaxf(fmaxf(x[0], x[1]), fmaxf(x[2], x[3]));
            rmax = fmaxf(rmax, __shfl_xor(rmax, 1));
            rmax = fmaxf(rmax, __shfl_xor(rmax, 2));
            rmax = fmaxf(rmax, __shfl_xor(rmax, 4));
            rmax = fmaxf(rmax, __shfl_xor(rmax, 8));
            float mn = fmaxf(m_[reg], rmax);
            float al = __expf(m_[reg] - mn);
            float ps = 0.f;
            const int prow = (g << 2) + reg;
            #pragma unroll
            for (int n = 0; n < 4; ++n) {
                float p = __expf(x[n] - mn);
                ps += p;
                int pcb = (((lane & 15) + (n << 4)) << 1) ^ ((prow & 7) << 4);
                *reinterpret_cast<unsigned short*>(
                    reinterpret_cast<char*>(Pw) + prow * 128 + pcb) = f2b(p);
            }
            ps += __shfl_xor(ps, 1);
            ps += __shfl_xor(ps, 2);
            ps += __shfl_xor(ps, 4);
            ps += __shfl_xor(ps, 8);
            l_[reg] = l_[reg] * al + ps;
            m_[reg] = mn;
            #pragma unroll
            for (int n = 0; n < 4; ++n) o[n][reg] *= al;
        }

        // O += P @ V
        #pragma unroll
        for (int ks = 0; ks < 2; ++ks) {
            bf16x8 pa = frag_ld(Pw, 0, ks);
            #pragma unroll
            for (int n = 0; n < 4; ++n)
                o[n] = __builtin_amdgcn_mfma_f32_16x16x32_bf16(
                    pa, frag_ld(Vs, n * 16, ks), o[n], 0, 0, 0);
        }
    }

    const int b = bh >> 4, h = bh & 15;
    float* ob = out + (size_t)(b * 2048 + qt * 64 + wid * 16) * 1024 + h * 64;
    #pragma unroll
    for (int reg = 0; reg < 4; ++reg) {
        float inv = 1.0f / l_[reg];
        int row = (g << 2) + reg;
        #pragma unroll
        for (int n = 0; n < 4; ++n)
            ob[(size_t)row * 1024 + n * 16 + (lane & 15)] = o[n][reg] * inv;
    }
}

// ---------------------------------------------------------------------------
extern "C" void kernel_launch(void* const* d_in, const int* in_sizes, int n_in,
                              void* d_out, int out_size, void* d_ws, size_t ws_size,
                              hipStream_t stream) {
    const float* x    = (const float*)d_in[0];
    const float* Wqkv = (const float*)d_in[1];
    const float* bqkv = (const float*)d_in[2];
    const float* Wp   = (const float*)d_in[3];
    const float* bp   = (const float*)d_in[4];
    float* out = (float*)d_out;

    const int B = 4, S = 2048, D = 1024;
    const int M = B * S;                       // 8192
    const size_t HSZ = (size_t)B * NH * S * HD;  // 8,388,608 elements

    unsigned short* qbuf = (unsigned short*)d_ws;
    unsigned short* kbuf = qbuf + HSZ;
    unsigned short* vtb  = kbuf + HSZ;
    float* attno = (float*)(vtb + HSZ);        // [M, D] fp32

    dim3 blk(256);
    gemm_qkv<<<dim3(3 * D / 64, M / 64), blk, 0, stream>>>(
        x, Wqkv, bqkv, qbuf, kbuf, vtb, M, 3 * D, D);
    attn_mfma<<<dim3(S / 64, B * NH), blk, 0, stream>>>(qbuf, kbuf, vtb, attno);
    gemm_bias<<<dim3(D / 64, M / 64), blk, 0, stream>>>(attno, Wp, bp, out, M, D, D);
}

// Round 3
// 381.303 us; speedup vs baseline: 11.7912x; 3.2104x over previous
//
#include <hip/hip_runtime.h>

#define NH 16
#define HD 64

typedef __attribute__((ext_vector_type(8))) _Float16 f16x8;
typedef __attribute__((ext_vector_type(4))) float f32x4;
typedef __attribute__((ext_vector_type(8))) unsigned short us8;
typedef __attribute__((ext_vector_type(4))) unsigned short us4;

__device__ __forceinline__ unsigned short f2h(float f) {
    _Float16 h = (_Float16)f;
    return __builtin_bit_cast(unsigned short, h);
}

// ---------------------------------------------------------------------------
// cast fp32 -> fp16, 4 elems/thread
// ---------------------------------------------------------------------------
__global__ __launch_bounds__(256)
void cast_f16(const float* __restrict__ in, unsigned short* __restrict__ out) {
    size_t i = ((size_t)blockIdx.x * 256 + threadIdx.x) * 4;
    float4 v = *reinterpret_cast<const float4*>(in + i);
    us4 w;
    w[0] = f2h(v.x); w[1] = f2h(v.y); w[2] = f2h(v.z); w[3] = f2h(v.w);
    *reinterpret_cast<us4*>(out + i) = w;
}

// ---------------------------------------------------------------------------
// transpose + cast: in fp32 [R,C] -> out fp16 [C,R].  64x64 tiles.
// ---------------------------------------------------------------------------
__global__ __launch_bounds__(256)
void transpose_cast(const float* __restrict__ in, unsigned short* __restrict__ out,
                    int R, int C) {
    __shared__ float T[64][65];
    const int c0 = blockIdx.x * 64, r0 = blockIdx.y * 64;
    const int tid = threadIdx.x;
    const int rr = tid >> 4, cc4 = (tid & 15) * 4;
    #pragma unroll
    for (int p = 0; p < 4; ++p) {
        int r = rr + p * 16;
        float4 v = *reinterpret_cast<const float4*>(
            in + (size_t)(r0 + r) * C + c0 + cc4);
        T[r][cc4] = v.x; T[r][cc4 + 1] = v.y; T[r][cc4 + 2] = v.z; T[r][cc4 + 3] = v.w;
    }
    __syncthreads();
    #pragma unroll
    for (int p = 0; p < 4; ++p) {
        int orow = rr + p * 16;     // output row = input col
        us4 w;
        #pragma unroll
        for (int j = 0; j < 4; ++j) w[j] = f2h(T[cc4 + j][orow]);
        *reinterpret_cast<us4*>(out + (size_t)(c0 + orow) * R + r0 + cc4) = w;
    }
}

// ---------------------------------------------------------------------------
// LDS staging with XOR swizzle (rows of 128B = 64 fp16).
// lds byte = r*128 + ((slot*16) ^ ((r&7)<<4))
// ---------------------------------------------------------------------------
__device__ __forceinline__ void stage128(unsigned short* dst,
                                         const unsigned short* src, int stride) {
    const int tid = threadIdx.x;
    #pragma unroll
    for (int p = 0; p < 4; ++p) {
        int idx = tid + p * 256;
        int r = idx >> 3;
        int slot = idx & 7;
        us8 v = *reinterpret_cast<const us8*>(src + (size_t)r * stride + slot * 8);
        int cb = (slot << 4) ^ ((r & 7) << 4);
        *reinterpret_cast<us8*>(reinterpret_cast<char*>(dst) + r * 128 + cb) = v;
    }
}

__device__ __forceinline__ void stage64(unsigned short* dst,
                                        const unsigned short* src, int stride) {
    const int tid = threadIdx.x;
    #pragma unroll
    for (int p = 0; p < 2; ++p) {
        int idx = tid + p * 256;
        int r = idx >> 3;
        int slot = idx & 7;
        us8 v = *reinterpret_cast<const us8*>(src + (size_t)r * stride + slot * 8);
        int cb = (slot << 4) ^ ((r & 7) << 4);
        *reinterpret_cast<us8*>(reinterpret_cast<char*>(dst) + r * 128 + cb) = v;
    }
}

// Fragment load: lane l -> row row0+(l&15), bytes [ks*64 + (l>>4)*16, +16) ^ swz
__device__ __forceinline__ f16x8 frag16(const unsigned short* base, int row0, int ks) {
    const int lane = threadIdx.x & 63;
    const int r = row0 + (lane & 15);
    int cb = ((ks << 6) + (lane & 48)) ^ ((r & 7) << 4);
    return *reinterpret_cast<const f16x8*>(
        reinterpret_cast<const char*>(base) + r * 128 + cb);
}

// ---------------------------------------------------------------------------
// MFMA GEMM core: C[M,N] = A[M,K] @ Bt[N,K]^T.  128x128 tile, BK=64, 4 waves.
// MODE 0: proj  (fp32 C + bias)
// MODE 1: qkv   (split into q,k [B,H,S,64] fp16 and v^T [B,H,64,S] fp16)
// ---------------------------------------------------------------------------
template<int MODE>
__global__ __launch_bounds__(256)
void gemm_f16(const unsigned short* __restrict__ A,
              const unsigned short* __restrict__ Bt,
              const float* __restrict__ bias,
              float* __restrict__ C,
              unsigned short* __restrict__ qb,
              unsigned short* __restrict__ kb,
              unsigned short* __restrict__ vtb,
              int M, int N, int K) {
    __shared__ __align__(16) unsigned short As[128 * 64];
    __shared__ __align__(16) unsigned short Bs[128 * 64];

    const int tid = threadIdx.x;
    const int wid = tid >> 6, lane = tid & 63, g = lane >> 4;
    const int wr = wid >> 1, wc = wid & 1;
    const int m0 = blockIdx.y * 128, n0 = blockIdx.x * 128;

    f32x4 acc[4][4];
    #pragma unroll
    for (int i = 0; i < 4; ++i)
        #pragma unroll
        for (int j = 0; j < 4; ++j) {
            acc[i][j][0] = 0.f; acc[i][j][1] = 0.f;
            acc[i][j][2] = 0.f; acc[i][j][3] = 0.f;
        }

    for (int k0 = 0; k0 < K; k0 += 64) {
        __syncthreads();
        stage128(As, A + (size_t)m0 * K + k0, K);
        stage128(Bs, Bt + (size_t)n0 * K + k0, K);
        __syncthreads();

        f16x8 af[4][2], bf[4][2];
        #pragma unroll
        for (int mi = 0; mi < 4; ++mi)
            #pragma unroll
            for (int ks = 0; ks < 2; ++ks)
                af[mi][ks] = frag16(As, wr * 64 + mi * 16, ks);
        #pragma unroll
        for (int ni = 0; ni < 4; ++ni)
            #pragma unroll
            for (int ks = 0; ks < 2; ++ks)
                bf[ni][ks] = frag16(Bs, wc * 64 + ni * 16, ks);

        #pragma unroll
        for (int ks = 0; ks < 2; ++ks)
            #pragma unroll
            for (int mi = 0; mi < 4; ++mi)
                #pragma unroll
                for (int ni = 0; ni < 4; ++ni)
                    acc[mi][ni] = __builtin_amdgcn_mfma_f32_16x16x32_f16(
                        af[mi][ks], bf[ni][ks], acc[mi][ni], 0, 0, 0);
    }

    const int colBase = n0 + wc * 64;
    const int rowBase = m0 + wr * 64;

    if (MODE == 0) {
        #pragma unroll
        for (int ni = 0; ni < 4; ++ni) {
            int col = colBase + ni * 16 + (lane & 15);
            float bv = bias[col];
            #pragma unroll
            for (int mi = 0; mi < 4; ++mi) {
                int row = rowBase + mi * 16 + g * 4;
                #pragma unroll
                for (int reg = 0; reg < 4; ++reg)
                    C[(size_t)(row + reg) * N + col] = acc[mi][ni][reg] + bv;
            }
        }
    } else {
        #pragma unroll
        for (int ni = 0; ni < 4; ++ni) {
            int col = colBase + ni * 16 + (lane & 15);
            float bv = bias[col];
            int seg = col >> 10;
            int cc = col & 1023;
            int h = cc >> 6, d = cc & 63;
            #pragma unroll
            for (int mi = 0; mi < 4; ++mi) {
                int row = rowBase + mi * 16 + g * 4;
                int b = row >> 11, s = row & 2047;
                size_t bh = (size_t)(b * NH + h);
                if (seg < 2) {
                    unsigned short* dst = (seg ? kb : qb)
                        + bh * 2048 * 64 + (size_t)s * 64 + d;
                    #pragma unroll
                    for (int reg = 0; reg < 4; ++reg)
                        dst[(size_t)reg * 64] = f2h(acc[mi][ni][reg] + bv);
                } else {
                    unsigned short* dst = vtb
                        + bh * 64 * 2048 + (size_t)d * 2048 + s;
                    us4 w;
                    #pragma unroll
                    for (int reg = 0; reg < 4; ++reg)
                        w[reg] = f2h(acc[mi][ni][reg] + bv);
                    *reinterpret_cast<us4*>(dst) = w;
                }
            }
        }
    }
}

// ---------------------------------------------------------------------------
// MFMA flash attention (fp16 operands). 4 waves, 64 q-rows, KV tiles of 64.
// Emits fp16 attno [B*S, D].
// ---------------------------------------------------------------------------
__global__ __launch_bounds__(256)
void attn_mfma(const unsigned short* __restrict__ qb,
               const unsigned short* __restrict__ kb,
               const unsigned short* __restrict__ vtb,
               unsigned short* __restrict__ attno) {
    const int bh = blockIdx.y;
    const int qt = blockIdx.x;
    const int tid = threadIdx.x;
    const int wid = tid >> 6;
    const int lane = tid & 63;
    const int g = lane >> 4;

    __shared__ __align__(16) unsigned short Qs[64 * 64];
    __shared__ __align__(16) unsigned short Ks[64 * 64];
    __shared__ __align__(16) unsigned short Vs[64 * 64];
    __shared__ __align__(16) unsigned short Ps[4][16 * 64];

    const unsigned short* qg  = qb  + ((size_t)bh * 2048 + (size_t)qt * 64) * 64;
    const unsigned short* kg0 = kb  + (size_t)bh * 2048 * 64;
    const unsigned short* vg0 = vtb + (size_t)bh * 64 * 2048;

    stage64(Qs, qg, 64);
    __syncthreads();
    const f16x8 qf0 = frag16(Qs, wid * 16, 0);
    const f16x8 qf1 = frag16(Qs, wid * 16, 1);

    f32x4 o[4];
    float m_[4], l_[4];
    #pragma unroll
    for (int n = 0; n < 4; ++n) { o[n][0] = 0.f; o[n][1] = 0.f; o[n][2] = 0.f; o[n][3] = 0.f; }
    #pragma unroll
    for (int r = 0; r < 4; ++r) { m_[r] = -1e30f; l_[r] = 0.f; }

    for (int kt = 0; kt <= qt; ++kt) {
        __syncthreads();
        stage64(Ks, kg0 + (size_t)kt * 64 * 64, 64);
        stage64(Vs, vg0 + (size_t)kt * 64, 2048);
        __syncthreads();

        f32x4 s[4];
        #pragma unroll
        for (int n = 0; n < 4; ++n) { s[n][0] = 0.f; s[n][1] = 0.f; s[n][2] = 0.f; s[n][3] = 0.f; }
        #pragma unroll
        for (int ks = 0; ks < 2; ++ks) {
            f16x8 a = ks ? qf1 : qf0;
            #pragma unroll
            for (int n = 0; n < 4; ++n)
                s[n] = __builtin_amdgcn_mfma_f32_16x16x32_f16(
                    a, frag16(Ks, n * 16, ks), s[n], 0, 0, 0);
        }

        unsigned short* Pw = Ps[wid];
        const int kc0 = kt * 64 + (lane & 15);
        const int qr0 = qt * 64 + wid * 16 + (g << 2);
        const bool diag = (kt == qt);

        #pragma unroll
        for (int reg = 0; reg < 4; ++reg) {
            float x[4];
            #pragma unroll
            for (int n = 0; n < 4; ++n) {
                x[n] = s[n][reg] * 0.125f;
                if (diag && (kc0 + 16 * n > qr0 + reg)) x[n] = -10000.0f;
            }
            float rmax = fmaxf(fmaxf(x[0], x[1]), fmaxf(x[2], x[3]));
            rmax = fmaxf(rmax, __shfl_xor(rmax, 1));
            rmax = fmaxf(rmax, __shfl_xor(rmax, 2));
            rmax = fmaxf(rmax, __shfl_xor(rmax, 4));
            rmax = fmaxf(rmax, __shfl_xor(rmax, 8));
            float mn = fmaxf(m_[reg], rmax);
            float al = __expf(m_[reg] - mn);
            float ps = 0.f;
            const int prow = (g << 2) + reg;
            #pragma unroll
            for (int n = 0; n < 4; ++n) {
                float p = __expf(x[n] - mn);
                ps += p;
                int pcb = (((lane & 15) + (n << 4)) << 1) ^ ((prow & 7) << 4);
                *reinterpret_cast<unsigned short*>(
                    reinterpret_cast<char*>(Pw) + prow * 128 + pcb) = f2h(p);
            }
            ps += __shfl_xor(ps, 1);
            ps += __shfl_xor(ps, 2);
            ps += __shfl_xor(ps, 4);
            ps += __shfl_xor(ps, 8);
            l_[reg] = l_[reg] * al + ps;
            m_[reg] = mn;
            #pragma unroll
            for (int n = 0; n < 4; ++n) o[n][reg] *= al;
        }

        #pragma unroll
        for (int ks = 0; ks < 2; ++ks) {
            f16x8 pa = frag16(Pw, 0, ks);
            #pragma unroll
            for (int n = 0; n < 4; ++n)
                o[n] = __builtin_amdgcn_mfma_f32_16x16x32_f16(
                    pa, frag16(Vs, n * 16, ks), o[n], 0, 0, 0);
        }
    }

    const int b = bh >> 4, h = bh & 15;
    unsigned short* ob = attno
        + (size_t)(b * 2048 + qt * 64 + wid * 16) * 1024 + h * 64;
    #pragma unroll
    for (int reg = 0; reg < 4; ++reg) {
        float inv = 1.0f / l_[reg];
        int row = (g << 2) + reg;
        #pragma unroll
        for (int n = 0; n < 4; ++n)
            ob[(size_t)row * 1024 + n * 16 + (lane & 15)] = f2h(o[n][reg] * inv);
    }
}

// ---------------------------------------------------------------------------
extern "C" void kernel_launch(void* const* d_in, const int* in_sizes, int n_in,
                              void* d_out, int out_size, void* d_ws, size_t ws_size,
                              hipStream_t stream) {
    const float* x    = (const float*)d_in[0];
    const float* Wqkv = (const float*)d_in[1];
    const float* bqkv = (const float*)d_in[2];
    const float* Wp   = (const float*)d_in[3];
    const float* bp   = (const float*)d_in[4];
    float* out = (float*)d_out;

    const int B = 4, S = 2048, D = 1024;
    const int M = B * S;                         // 8192
    const size_t HSZ = (size_t)M * D;            // 8 M elems

    unsigned short* xh    = (unsigned short*)d_ws;   // [M,D]      fp16
    unsigned short* wqt   = xh + HSZ;                // [3D,D]     fp16
    unsigned short* wpt   = wqt + (size_t)3 * D * D; // [D,D]      fp16
    unsigned short* qbuf  = wpt + (size_t)D * D;     // [B,H,S,64]
    unsigned short* kbuf  = qbuf + HSZ;
    unsigned short* vtb   = kbuf + HSZ;
    unsigned short* attno = vtb + HSZ;               // [M,D] fp16

    dim3 blk(256);
    cast_f16<<<dim3((int)(HSZ / 1024)), blk, 0, stream>>>(x, xh);
    transpose_cast<<<dim3(3 * D / 64, D / 64), blk, 0, stream>>>(Wqkv, wqt, D, 3 * D);
    transpose_cast<<<dim3(D / 64, D / 64), blk, 0, stream>>>(Wp, wpt, D, D);

    gemm_f16<1><<<dim3(3 * D / 128, M / 128), blk, 0, stream>>>(
        xh, wqt, bqkv, nullptr, qbuf, kbuf, vtb, M, 3 * D, D);
    attn_mfma<<<dim3(S / 64, B * NH), blk, 0, stream>>>(qbuf, kbuf, vtb, attno);
    gemm_f16<0><<<dim3(D / 128, M / 128), blk, 0, stream>>>(
        attno, wpt, bp, out, nullptr, nullptr, nullptr, M, D, D);
}

// Round 4
// 263.557 us; speedup vs baseline: 17.0590x; 1.4468x over previous
//
#include <hip/hip_runtime.h>

#define NH 16
#define HD 64

typedef __attribute__((ext_vector_type(8))) _Float16 f16x8;
typedef __attribute__((ext_vector_type(4))) float f32x4;
typedef __attribute__((ext_vector_type(8))) unsigned short us8;
typedef __attribute__((ext_vector_type(4))) unsigned short us4;

__device__ __forceinline__ unsigned short f2h(float f) {
    _Float16 h = (_Float16)f;
    return __builtin_bit_cast(unsigned short, h);
}

// ---------------------------------------------------------------------------
// cast fp32 -> fp16, 4 elems/thread
// ---------------------------------------------------------------------------
__global__ __launch_bounds__(256)
void cast_f16(const float* __restrict__ in, unsigned short* __restrict__ out) {
    size_t i = ((size_t)blockIdx.x * 256 + threadIdx.x) * 4;
    float4 v = *reinterpret_cast<const float4*>(in + i);
    us4 w;
    w[0] = f2h(v.x); w[1] = f2h(v.y); w[2] = f2h(v.z); w[3] = f2h(v.w);
    *reinterpret_cast<us4*>(out + i) = w;
}

// ---------------------------------------------------------------------------
// transpose + cast: in fp32 [R,C] -> out fp16 [C,R].  64x64 tiles.
// ---------------------------------------------------------------------------
__global__ __launch_bounds__(256)
void transpose_cast(const float* __restrict__ in, unsigned short* __restrict__ out,
                    int R, int C) {
    __shared__ float T[64][65];
    const int c0 = blockIdx.x * 64, r0 = blockIdx.y * 64;
    const int tid = threadIdx.x;
    const int rr = tid >> 4, cc4 = (tid & 15) * 4;
    #pragma unroll
    for (int p = 0; p < 4; ++p) {
        int r = rr + p * 16;
        float4 v = *reinterpret_cast<const float4*>(
            in + (size_t)(r0 + r) * C + c0 + cc4);
        T[r][cc4] = v.x; T[r][cc4 + 1] = v.y; T[r][cc4 + 2] = v.z; T[r][cc4 + 3] = v.w;
    }
    __syncthreads();
    #pragma unroll
    for (int p = 0; p < 4; ++p) {
        int orow = rr + p * 16;     // output row = input col
        us4 w;
        #pragma unroll
        for (int j = 0; j < 4; ++j) w[j] = f2h(T[cc4 + j][orow]);
        *reinterpret_cast<us4*>(out + (size_t)(c0 + orow) * R + r0 + cc4) = w;
    }
}

// ---------------------------------------------------------------------------
// LDS staging with XOR swizzle (rows of 128B = 64 fp16).
// lds byte = r*128 + ((slot*16) ^ ((r&7)<<4))
// ---------------------------------------------------------------------------
__device__ __forceinline__ void stage128(unsigned short* dst,
                                         const unsigned short* src, int stride) {
    const int tid = threadIdx.x;
    #pragma unroll
    for (int p = 0; p < 4; ++p) {
        int idx = tid + p * 256;
        int r = idx >> 3;
        int slot = idx & 7;
        us8 v = *reinterpret_cast<const us8*>(src + (size_t)r * stride + slot * 8);
        int cb = (slot << 4) ^ ((r & 7) << 4);
        *reinterpret_cast<us8*>(reinterpret_cast<char*>(dst) + r * 128 + cb) = v;
    }
}

__device__ __forceinline__ void stage64(unsigned short* dst,
                                        const unsigned short* src, int stride) {
    const int tid = threadIdx.x;
    #pragma unroll
    for (int p = 0; p < 2; ++p) {
        int idx = tid + p * 256;
        int r = idx >> 3;
        int slot = idx & 7;
        us8 v = *reinterpret_cast<const us8*>(src + (size_t)r * stride + slot * 8);
        int cb = (slot << 4) ^ ((r & 7) << 4);
        *reinterpret_cast<us8*>(reinterpret_cast<char*>(dst) + r * 128 + cb) = v;
    }
}

// Fragment load: lane l -> row row0+(l&15), bytes [ks*64 + (l>>4)*16, +16) ^ swz
__device__ __forceinline__ f16x8 frag16(const unsigned short* base, int row0, int ks) {
    const int lane = threadIdx.x & 63;
    const int r = row0 + (lane & 15);
    int cb = ((ks << 6) + (lane & 48)) ^ ((r & 7) << 4);
    return *reinterpret_cast<const f16x8*>(
        reinterpret_cast<const char*>(base) + r * 128 + cb);
}

// ---------------------------------------------------------------------------
// MFMA GEMM core: C[M,N] = A[M,K] @ Bt[N,K]^T.  128x128 tile, BK=64, 4 waves.
// MODE 0: proj  (fp32 C + bias)
// MODE 1: qkv   (split into q,k [B,H,S,64] fp16 and v^T [B,H,64,S] fp16)
// ---------------------------------------------------------------------------
template<int MODE>
__global__ __launch_bounds__(256)
void gemm_f16(const unsigned short* __restrict__ A,
              const unsigned short* __restrict__ Bt,
              const float* __restrict__ bias,
              float* __restrict__ C,
              unsigned short* __restrict__ qb,
              unsigned short* __restrict__ kb,
              unsigned short* __restrict__ vtb,
              int M, int N, int K) {
    __shared__ __align__(16) unsigned short As[128 * 64];
    __shared__ __align__(16) unsigned short Bs[128 * 64];

    const int tid = threadIdx.x;
    const int wid = tid >> 6, lane = tid & 63, g = lane >> 4;
    const int wr = wid >> 1, wc = wid & 1;
    const int m0 = blockIdx.y * 128, n0 = blockIdx.x * 128;

    f32x4 acc[4][4];
    #pragma unroll
    for (int i = 0; i < 4; ++i)
        #pragma unroll
        for (int j = 0; j < 4; ++j) {
            acc[i][j][0] = 0.f; acc[i][j][1] = 0.f;
            acc[i][j][2] = 0.f; acc[i][j][3] = 0.f;
        }

    for (int k0 = 0; k0 < K; k0 += 64) {
        __syncthreads();
        stage128(As, A + (size_t)m0 * K + k0, K);
        stage128(Bs, Bt + (size_t)n0 * K + k0, K);
        __syncthreads();

        f16x8 af[4][2], bf[4][2];
        #pragma unroll
        for (int mi = 0; mi < 4; ++mi)
            #pragma unroll
            for (int ks = 0; ks < 2; ++ks)
                af[mi][ks] = frag16(As, wr * 64 + mi * 16, ks);
        #pragma unroll
        for (int ni = 0; ni < 4; ++ni)
            #pragma unroll
            for (int ks = 0; ks < 2; ++ks)
                bf[ni][ks] = frag16(Bs, wc * 64 + ni * 16, ks);

        __builtin_amdgcn_s_setprio(1);
        #pragma unroll
        for (int ks = 0; ks < 2; ++ks)
            #pragma unroll
            for (int mi = 0; mi < 4; ++mi)
                #pragma unroll
                for (int ni = 0; ni < 4; ++ni)
                    acc[mi][ni] = __builtin_amdgcn_mfma_f32_16x16x32_f16(
                        af[mi][ks], bf[ni][ks], acc[mi][ni], 0, 0, 0);
        __builtin_amdgcn_s_setprio(0);
    }

    const int colBase = n0 + wc * 64;
    const int rowBase = m0 + wr * 64;

    if (MODE == 0) {
        #pragma unroll
        for (int ni = 0; ni < 4; ++ni) {
            int col = colBase + ni * 16 + (lane & 15);
            float bv = bias[col];
            #pragma unroll
            for (int mi = 0; mi < 4; ++mi) {
                int row = rowBase + mi * 16 + g * 4;
                #pragma unroll
                for (int reg = 0; reg < 4; ++reg)
                    C[(size_t)(row + reg) * N + col] = acc[mi][ni][reg] + bv;
            }
        }
    } else {
        #pragma unroll
        for (int ni = 0; ni < 4; ++ni) {
            int col = colBase + ni * 16 + (lane & 15);
            float bv = bias[col];
            int seg = col >> 10;
            int cc = col & 1023;
            int h = cc >> 6, d = cc & 63;
            #pragma unroll
            for (int mi = 0; mi < 4; ++mi) {
                int row = rowBase + mi * 16 + g * 4;
                int b = row >> 11, s = row & 2047;
                size_t bh = (size_t)(b * NH + h);
                if (seg < 2) {
                    unsigned short* dst = (seg ? kb : qb)
                        + bh * 2048 * 64 + (size_t)s * 64 + d;
                    #pragma unroll
                    for (int reg = 0; reg < 4; ++reg)
                        dst[(size_t)reg * 64] = f2h(acc[mi][ni][reg] + bv);
                } else {
                    unsigned short* dst = vtb
                        + bh * 64 * 2048 + (size_t)d * 2048 + s;
                    us4 w;
                    #pragma unroll
                    for (int reg = 0; reg < 4; ++reg)
                        w[reg] = f2h(acc[mi][ni][reg] + bv);
                    *reinterpret_cast<us4*>(dst) = w;
                }
            }
        }
    }
}

// ---------------------------------------------------------------------------
// One (16q x 64k) attention tile for one wave: QK^T, online softmax, PV.
// Identical math to round-3 inner loop.
// ---------------------------------------------------------------------------
__device__ __forceinline__ void attn_tile(
    f16x8 qf0, f16x8 qf1,
    const unsigned short* Ks, const unsigned short* Vs, unsigned short* Pw,
    f32x4 (&o)[4], float (&m_)[4], float (&l_)[4],
    int qt, int kt, int qrow_base, int lane, int g) {

    f32x4 s[4];
    #pragma unroll
    for (int n = 0; n < 4; ++n) { s[n][0] = 0.f; s[n][1] = 0.f; s[n][2] = 0.f; s[n][3] = 0.f; }

    __builtin_amdgcn_s_setprio(1);
    #pragma unroll
    for (int ks = 0; ks < 2; ++ks) {
        f16x8 a = ks ? qf1 : qf0;
        #pragma unroll
        for (int n = 0; n < 4; ++n)
            s[n] = __builtin_amdgcn_mfma_f32_16x16x32_f16(
                a, frag16(Ks, n * 16, ks), s[n], 0, 0, 0);
    }
    __builtin_amdgcn_s_setprio(0);

    const int kc0 = kt * 64 + (lane & 15);
    const int qr0 = qrow_base + (g << 2);
    const bool diag = (kt == qt);

    #pragma unroll
    for (int reg = 0; reg < 4; ++reg) {
        float x[4];
        #pragma unroll
        for (int n = 0; n < 4; ++n) {
            x[n] = s[n][reg] * 0.125f;
            if (diag && (kc0 + 16 * n > qr0 + reg)) x[n] = -10000.0f;
        }
        float rmax = fmaxf(fmaxf(x[0], x[1]), fmaxf(x[2], x[3]));
        rmax = fmaxf(rmax, __shfl_xor(rmax, 1));
        rmax = fmaxf(rmax, __shfl_xor(rmax, 2));
        rmax = fmaxf(rmax, __shfl_xor(rmax, 4));
        rmax = fmaxf(rmax, __shfl_xor(rmax, 8));
        float mn = fmaxf(m_[reg], rmax);
        float al = __expf(m_[reg] - mn);
        float ps = 0.f;
        const int prow = (g << 2) + reg;
        #pragma unroll
        for (int n = 0; n < 4; ++n) {
            float p = __expf(x[n] - mn);
            ps += p;
            int pcb = (((lane & 15) + (n << 4)) << 1) ^ ((prow & 7) << 4);
            *reinterpret_cast<unsigned short*>(
                reinterpret_cast<char*>(Pw) + prow * 128 + pcb) = f2h(p);
        }
        ps += __shfl_xor(ps, 1);
        ps += __shfl_xor(ps, 2);
        ps += __shfl_xor(ps, 4);
        ps += __shfl_xor(ps, 8);
        l_[reg] = l_[reg] * al + ps;
        m_[reg] = mn;
        #pragma unroll
        for (int n = 0; n < 4; ++n) o[n][reg] *= al;
    }

    __builtin_amdgcn_s_setprio(1);
    #pragma unroll
    for (int ks = 0; ks < 2; ++ks) {
        f16x8 pa = frag16(Pw, 0, ks);
        #pragma unroll
        for (int n = 0; n < 4; ++n)
            o[n] = __builtin_amdgcn_mfma_f32_16x16x32_f16(
                pa, frag16(Vs, n * 16, ks), o[n], 0, 0, 0);
    }
    __builtin_amdgcn_s_setprio(0);
}

// ---------------------------------------------------------------------------
// MFMA flash attention with diagonal pairing: block = 4 waves, handles
// q-tiles {pair, 31-pair} sharing one K/V staging loop -> uniform work (33
// tile-units per block).  Q frags direct from global (no Qs LDS).
// ---------------------------------------------------------------------------
__global__ __launch_bounds__(256, 4)
void attn_mfma(const unsigned short* __restrict__ qb,
               const unsigned short* __restrict__ kb,
               const unsigned short* __restrict__ vtb,
               unsigned short* __restrict__ attno) {
    const int bh = blockIdx.y;
    const int pair = blockIdx.x;            // 0..15
    const int qtA = pair, qtB = 31 - pair;
    const int tid = threadIdx.x;
    const int wid = tid >> 6, lane = tid & 63, g = lane >> 4;

    __shared__ __align__(16) unsigned short Ks[64 * 64];
    __shared__ __align__(16) unsigned short Vs[64 * 64];
    __shared__ __align__(16) unsigned short Ps[4][16 * 64];

    const unsigned short* kg0 = kb + (size_t)bh * 2048 * 64;
    const unsigned short* vg0 = vtb + (size_t)bh * 64 * 2048;

    // Q fragments direct from global: row = qt*64 + wid*16 + (lane&15),
    // elems [ks*32 + (lane>>4)*8, +8)
    const int qrl = wid * 16 + (lane & 15);
    const int qd0 = (lane >> 4) * 8;
    const unsigned short* qbase = qb + (size_t)bh * 2048 * 64;
    f16x8 qA0 = *reinterpret_cast<const f16x8*>(qbase + (size_t)(qtA * 64 + qrl) * 64 + qd0);
    f16x8 qA1 = *reinterpret_cast<const f16x8*>(qbase + (size_t)(qtA * 64 + qrl) * 64 + 32 + qd0);
    f16x8 qB0 = *reinterpret_cast<const f16x8*>(qbase + (size_t)(qtB * 64 + qrl) * 64 + qd0);
    f16x8 qB1 = *reinterpret_cast<const f16x8*>(qbase + (size_t)(qtB * 64 + qrl) * 64 + 32 + qd0);

    f32x4 oA[4], oB[4];
    float mA[4], lA[4], mB[4], lB[4];
    #pragma unroll
    for (int n = 0; n < 4; ++n) {
        #pragma unroll
        for (int r = 0; r < 4; ++r) { oA[n][r] = 0.f; oB[n][r] = 0.f; }
    }
    #pragma unroll
    for (int r = 0; r < 4; ++r) { mA[r] = -1e30f; lA[r] = 0.f; mB[r] = -1e30f; lB[r] = 0.f; }

    unsigned short* Pw = Ps[wid];
    const int qrbA = qtA * 64 + wid * 16;
    const int qrbB = qtB * 64 + wid * 16;

    for (int kt = 0; kt <= qtB; ++kt) {
        __syncthreads();
        stage64(Ks, kg0 + (size_t)kt * 64 * 64, 64);
        stage64(Vs, vg0 + (size_t)kt * 64, 2048);
        __syncthreads();

        attn_tile(qB0, qB1, Ks, Vs, Pw, oB, mB, lB, qtB, kt, qrbB, lane, g);
        if (kt <= qtA)
            attn_tile(qA0, qA1, Ks, Vs, Pw, oA, mA, lA, qtA, kt, qrbA, lane, g);
    }

    const int b = bh >> 4, h = bh & 15;
    #pragma unroll
    for (int ph = 0; ph < 2; ++ph) {
        const int qt = ph ? qtB : qtA;
        f32x4* o = ph ? oB : oA;
        float* l_ = ph ? lB : lA;
        unsigned short* ob = attno
            + (size_t)(b * 2048 + qt * 64 + wid * 16) * 1024 + h * 64;
        #pragma unroll
        for (int reg = 0; reg < 4; ++reg) {
            float inv = 1.0f / l_[reg];
            int row = (g << 2) + reg;
            #pragma unroll
            for (int n = 0; n < 4; ++n)
                ob[(size_t)row * 1024 + n * 16 + (lane & 15)] = f2h(o[n][reg] * inv);
        }
    }
}

// ---------------------------------------------------------------------------
extern "C" void kernel_launch(void* const* d_in, const int* in_sizes, int n_in,
                              void* d_out, int out_size, void* d_ws, size_t ws_size,
                              hipStream_t stream) {
    const float* x    = (const float*)d_in[0];
    const float* Wqkv = (const float*)d_in[1];
    const float* bqkv = (const float*)d_in[2];
    const float* Wp   = (const float*)d_in[3];
    const float* bp   = (const float*)d_in[4];
    float* out = (float*)d_out;

    const int B = 4, S = 2048, D = 1024;
    const int M = B * S;                         // 8192
    const size_t HSZ = (size_t)M * D;            // 8 M elems

    unsigned short* xh    = (unsigned short*)d_ws;   // [M,D]      fp16
    unsigned short* wqt   = xh + HSZ;                // [3D,D]     fp16
    unsigned short* wpt   = wqt + (size_t)3 * D * D; // [D,D]      fp16
    unsigned short* qbuf  = wpt + (size_t)D * D;     // [B,H,S,64]
    unsigned short* kbuf  = qbuf + HSZ;
    unsigned short* vtb   = kbuf + HSZ;
    unsigned short* attno = vtb + HSZ;               // [M,D] fp16

    dim3 blk(256);
    cast_f16<<<dim3((int)(HSZ / 1024)), blk, 0, stream>>>(x, xh);
    transpose_cast<<<dim3(3 * D / 64, D / 64), blk, 0, stream>>>(Wqkv, wqt, D, 3 * D);
    transpose_cast<<<dim3(D / 64, D / 64), blk, 0, stream>>>(Wp, wpt, D, D);

    gemm_f16<1><<<dim3(3 * D / 128, M / 128), blk, 0, stream>>>(
        xh, wqt, bqkv, nullptr, qbuf, kbuf, vtb, M, 3 * D, D);
    attn_mfma<<<dim3(16, 64), blk, 0, stream>>>(qbuf, kbuf, vtb, attno);
    gemm_f16<0><<<dim3(D / 128, M / 128), blk, 0, stream>>>(
        attno, wpt, bp, out, nullptr, nullptr, nullptr, M, D, D);
}